// Round 7
// baseline (240.264 us; speedup 1.0000x reference)
//
#include <hip/hip_runtime.h>
#include <stdint.h>

typedef unsigned short u16;
typedef __attribute__((ext_vector_type(8))) short short8;   // 8 bf16 in 4 VGPRs
typedef __attribute__((ext_vector_type(4))) float f32x4;

// ---------- bf16 helpers ----------
__device__ __forceinline__ float bf2f(u16 u) {
    union { unsigned u; float f; } x; x.u = ((unsigned)u) << 16; return x.f;
}
__device__ __forceinline__ float bf_lo(unsigned w) {
    union { unsigned u; float f; } x; x.u = w << 16; return x.f;
}
__device__ __forceinline__ float bf_hi(unsigned w) {
    union { unsigned u; float f; } x; x.u = w & 0xffff0000u; return x.f;
}
__device__ __forceinline__ u16 f2bf(float f) {   // round-to-nearest-even
    union { float f; unsigned u; } x; x.f = f;
    unsigned r = x.u + 0x7fffu + ((x.u >> 16) & 1u);
    return (u16)(r >> 16);
}
__device__ __forceinline__ uint4 cvt8(const float* p) {
    float4 a = *reinterpret_cast<const float4*>(p);
    float4 b = *reinterpret_cast<const float4*>(p + 4);
    uint4 r;
    r.x = (unsigned)f2bf(a.x) | ((unsigned)f2bf(a.y) << 16);
    r.y = (unsigned)f2bf(a.z) | ((unsigned)f2bf(a.w) << 16);
    r.z = (unsigned)f2bf(b.x) | ((unsigned)f2bf(b.y) << 16);
    r.w = (unsigned)f2bf(b.z) | ((unsigned)f2bf(b.w) << 16);
    return r;
}

// async global -> LDS, 16 bytes per lane (lds dest = wave-uniform base + lane*16)
__device__ __forceinline__ void gl16(const u16* g, u16* l) {
    __builtin_amdgcn_global_load_lds(
        (const __attribute__((address_space(1))) void*)g,
        (__attribute__((address_space(3))) void*)l, 16, 0, 0);
}

// ---------- fp32 -> bf16 bulk converts ----------
__global__ __launch_bounds__(256) void cvt_kernel(const float* __restrict__ in,
                                                  u16* __restrict__ out, int n8) {
    int i = blockIdx.x * 256 + threadIdx.x;
    if (i < n8) *reinterpret_cast<uint4*>(&out[(size_t)i * 8]) = cvt8(&in[(size_t)i * 8]);
}

// fused 3-array convert into one contiguous bf16 region
__global__ __launch_bounds__(256) void cvt3_kernel(const float* __restrict__ a, int na8,
                                                   const float* __restrict__ b, int nb8,
                                                   const float* __restrict__ c, int nc8,
                                                   u16* __restrict__ dst) {
    int i = blockIdx.x * 256 + threadIdx.x;
    const float* src; int off;
    if (i < na8)            { src = a; off = i; }
    else if (i < na8 + nb8) { src = b; off = i - na8; }
    else if (i < na8 + nb8 + nc8) { src = c; off = i - na8 - nb8; }
    else return;
    *reinterpret_cast<uint4*>(&dst[(size_t)i * 8]) = cvt8(&src[(size_t)off * 8]);
}

#define BM 128
#define BN 128
#define BK 32
#define BKA 64

// ============================================================
// m97-class GEMM, BK=64, SINGLE-buffered (R4 structure — dbuf regressed:
// 64KB LDS halves blocks/CU and inter-block overlap beats intra-block
// prefetch distance, m99/m132 lesson re-measured in R5).
// XOR swizzle: LDS slot (row r, chunk c) holds global chunk c ^ (r&7);
// ds_read_b128 serviced in 8-lane groups -> all 8 chunks covered -> 0 conflicts.
// If vt != nullptr, blocks with col0 >= 2048 write transposed V:
// vt[(b*1024 + (col-2048))*1024 + t]  (fused vtrans).
// ============================================================
template<bool CF32>
__global__ __launch_bounds__(256) void gemm_bt_a(const u16* __restrict__ A,
                                                 const u16* __restrict__ W,
                                                 void* __restrict__ Cv,
                                                 const float* __restrict__ bias,
                                                 int M, int N, int K, int lda,
                                                 u16* __restrict__ vt) {
    __shared__ __align__(16) u16 As[BM * BKA];   // 16 KB
    __shared__ __align__(16) u16 Ws[BN * BKA];   // 16 KB

    const int tid  = threadIdx.x;
    const int lane = tid & 63;
    const int w    = tid >> 6;
    const int wr   = w >> 1;
    const int wc   = w & 1;
    const int quad = lane >> 4;
    const int l16  = lane & 15;

    const int row0 = blockIdx.y * BM;
    const int col0 = blockIdx.x * BN;

    // staging: pass p covers rows p*32 + w*8 + (l>>3); global chunk (l&7)^(l>>3)
    const int srow = w * 8 + (lane >> 3);
    const int gc   = (lane & 7) ^ (lane >> 3);

    const u16* gA[4]; const u16* gW[4]; u16* lA[4]; u16* lW[4];
#pragma unroll
    for (int p = 0; p < 4; p++) {
        gA[p] = A + (size_t)(row0 + p * 32 + srow) * lda + gc * 8;
        gW[p] = W + (size_t)(col0 + p * 32 + srow) * K  + gc * 8;
        lA[p] = &As[(p * 32 + w * 8) * BKA];
        lW[p] = &Ws[(p * 32 + w * 8) * BKA];
    }

    // swizzled frag-read column: chunk (ks*4+quad) ^ (l16&7)
    const int cr0 = (quad ^ (l16 & 7)) * 8;

    f32x4 acc[4][4] = {};

    for (int k0 = 0; k0 < K; k0 += BKA) {
        __syncthreads();
#pragma unroll
        for (int p = 0; p < 4; p++) {
            gl16(gA[p] + k0, lA[p]);
            gl16(gW[p] + k0, lW[p]);
        }
        __syncthreads();   // vmcnt drain before barrier (m97 structure)

#pragma unroll
        for (int ks = 0; ks < 2; ks++) {
            const int cc = cr0 ^ (ks * 32);
            short8 af[4], bfr[4];
#pragma unroll
            for (int i = 0; i < 4; i++)
                af[i] = *reinterpret_cast<const short8*>(&As[(wr * 64 + i * 16 + l16) * BKA + cc]);
#pragma unroll
            for (int j = 0; j < 4; j++)
                bfr[j] = *reinterpret_cast<const short8*>(&Ws[(wc * 64 + j * 16 + l16) * BKA + cc]);
#pragma unroll
            for (int i = 0; i < 4; i++)
#pragma unroll
                for (int j = 0; j < 4; j++)
                    acc[i][j] = __builtin_amdgcn_mfma_f32_16x16x32_bf16(af[i], bfr[j], acc[i][j], 0, 0, 0);
        }
    }

    // epilogue: C/D layout col=lane&15, row=quad*4+reg  [verified m89/m91]
    if (vt != nullptr && col0 >= 2048) {
        // fused V-transpose: 4 consecutive t per lane -> one 8B store
        const int b = row0 >> 10;
#pragma unroll
        for (int j = 0; j < 4; j++) {
            const int hd = col0 - 2048 + wc * 64 + j * 16 + l16;   // h*64+dh
            u16* dstc = vt + (size_t)(b * 1024 + hd) * 1024 + (row0 & 1023) + wr * 64;
#pragma unroll
            for (int i = 0; i < 4; i++) {
                const int t0 = i * 16 + quad * 4;
                u16 pk[4];
#pragma unroll
                for (int r = 0; r < 4; r++) pk[r] = f2bf(acc[i][j][r]);
                *reinterpret_cast<uint2*>(dstc + t0) = *reinterpret_cast<uint2*>(pk);
            }
        }
    } else {
#pragma unroll
        for (int j = 0; j < 4; j++) {
            const int col = col0 + wc * 64 + j * 16 + l16;
            const float bval = bias ? bias[col] : 0.0f;
#pragma unroll
            for (int i = 0; i < 4; i++) {
#pragma unroll
                for (int r = 0; r < 4; r++) {
                    const int row = row0 + wr * 64 + i * 16 + quad * 4 + r;
                    if (CF32) ((float*)Cv)[(size_t)row * N + col] = acc[i][j][r] + bval;
                    else      ((u16*)Cv)[(size_t)row * N + col]  = f2bf(acc[i][j][r] + bval);
                }
            }
        }
    }
}

// ============================================================
// fallback GEMM (fp32 staging paths, known-good R2)
// ============================================================
template<bool AF32, bool WF32, bool CF32>
__global__ __launch_bounds__(256) void gemm_bt(const void* __restrict__ Av,
                                               const void* __restrict__ Wv,
                                               void* __restrict__ Cv,
                                               const float* __restrict__ bias,
                                               int M, int N, int K, int lda) {
    __shared__ __align__(16) u16 As[BM * BK];
    __shared__ __align__(16) u16 Ws[BN * BK];

    const int tid  = threadIdx.x;
    const int lane = tid & 63;
    const int wave = tid >> 6;
    const int wr   = wave >> 1;
    const int wc   = wave & 1;
    const int quad = lane >> 4;
    const int l16  = lane & 15;

    const int row0 = blockIdx.y * BM;
    const int col0 = blockIdx.x * BN;

    const int sr = tid >> 2;
    const int sc = (tid & 3) * 8;

    f32x4 acc[4][4] = {};

    for (int k0 = 0; k0 < K; k0 += BK) {
        __syncthreads();
        if (AF32) {
            const float* A = (const float*)Av;
            *reinterpret_cast<uint4*>(&As[(sr)      * BK + sc]) = cvt8(&A[(size_t)(row0 + sr)      * lda + k0 + sc]);
            *reinterpret_cast<uint4*>(&As[(sr + 64) * BK + sc]) = cvt8(&A[(size_t)(row0 + sr + 64) * lda + k0 + sc]);
        } else {
            const u16* A = (const u16*)Av;
            *reinterpret_cast<uint4*>(&As[(sr)      * BK + sc]) =
                *reinterpret_cast<const uint4*>(&A[(size_t)(row0 + sr)      * lda + k0 + sc]);
            *reinterpret_cast<uint4*>(&As[(sr + 64) * BK + sc]) =
                *reinterpret_cast<const uint4*>(&A[(size_t)(row0 + sr + 64) * lda + k0 + sc]);
        }
        if (WF32) {
            const float* W = (const float*)Wv;
            *reinterpret_cast<uint4*>(&Ws[(sr)      * BK + sc]) = cvt8(&W[(size_t)(col0 + sr)      * K + k0 + sc]);
            *reinterpret_cast<uint4*>(&Ws[(sr + 64) * BK + sc]) = cvt8(&W[(size_t)(col0 + sr + 64) * K + k0 + sc]);
        } else {
            const u16* W = (const u16*)Wv;
            *reinterpret_cast<uint4*>(&Ws[(sr)      * BK + sc]) =
                *reinterpret_cast<const uint4*>(&W[(size_t)(col0 + sr)      * K + k0 + sc]);
            *reinterpret_cast<uint4*>(&Ws[(sr + 64) * BK + sc]) =
                *reinterpret_cast<const uint4*>(&W[(size_t)(col0 + sr + 64) * K + k0 + sc]);
        }
        __syncthreads();

        short8 af[4], bfr[4];
#pragma unroll
        for (int i = 0; i < 4; i++)
            af[i] = *reinterpret_cast<const short8*>(&As[(wr * 64 + i * 16 + l16) * BK + quad * 8]);
#pragma unroll
        for (int j = 0; j < 4; j++)
            bfr[j] = *reinterpret_cast<const short8*>(&Ws[(wc * 64 + j * 16 + l16) * BK + quad * 8]);

#pragma unroll
        for (int i = 0; i < 4; i++)
#pragma unroll
            for (int j = 0; j < 4; j++)
                acc[i][j] = __builtin_amdgcn_mfma_f32_16x16x32_bf16(af[i], bfr[j], acc[i][j], 0, 0, 0);
    }

#pragma unroll
    for (int j = 0; j < 4; j++) {
        const int col = col0 + wc * 64 + j * 16 + l16;
        const float bval = bias ? bias[col] : 0.0f;
#pragma unroll
        for (int i = 0; i < 4; i++) {
#pragma unroll
            for (int r = 0; r < 4; r++) {
                const int row = row0 + wr * 64 + i * 16 + quad * 4 + r;
                if (CF32) ((float*)Cv)[(size_t)row * N + col] = acc[i][j][r] + bval;
                else      ((u16*)Cv)[(size_t)row * N + col]  = f2bf(acc[i][j][r] + bval);
            }
        }
    }
}

// ============================================================
// V transpose (fallback tiers only): qkv v-section -> Vt[b][h][dh][t]
// ============================================================
__global__ __launch_bounds__(256) void vtrans_kernel(const u16* __restrict__ qkv,
                                                     u16* __restrict__ vt) {
    const int bid = blockIdx.x;
    const int tt = bid & 15, h = (bid >> 4) & 15, b = bid >> 8;
    const int t0 = tt * 64;
    __shared__ __align__(16) u16 tile[64 * 72];
    const int tr = threadIdx.x >> 2, tc = (threadIdx.x & 3) * 16;
    const u16* src = qkv + (size_t)(b * 1024 + t0 + tr) * 3072 + 2048 + h * 64 + tc;
    *reinterpret_cast<uint4*>(&tile[tr * 72 + tc])     = *reinterpret_cast<const uint4*>(src);
    *reinterpret_cast<uint4*>(&tile[tr * 72 + tc + 8]) = *reinterpret_cast<const uint4*>(src + 8);
    __syncthreads();
    const int dh = tr, t1 = tc;
    __align__(16) u16 buf[16];
#pragma unroll
    for (int i = 0; i < 16; i++) buf[i] = tile[(t1 + i) * 72 + dh];
    u16* dst = vt + ((size_t)(b * 16 + h) * 64 + dh) * 1024 + t0 + t1;
    *reinterpret_cast<uint4*>(dst)     = *reinterpret_cast<uint4*>(&buf[0]);
    *reinterpret_cast<uint4*>(dst + 8) = *reinterpret_cast<uint4*>(&buf[8]);
}

// ============================================================
// MFMA flash attention (S^T formulation).
// R6: K/V staged via global_load_lds (width=16) with the GEMM's XOR
// swizzle; Ks/Vs stride = 64 (gl16 forbids padding), reads conflict-free
// because 8 consecutive lanes cover all 8 chunk positions.
// ============================================================
#define SK 72   // Ps stride (normal ds_write, padded)

__global__ __launch_bounds__(256) void fattn_kernel(u16* __restrict__ qkv,
                                                    const u16* __restrict__ vt) {
    __shared__ __align__(16) u16 Ks[64 * 64];
    __shared__ __align__(16) u16 Vs[64 * 64];
    __shared__ __align__(16) u16 Ps[4][32 * SK];
    __shared__ __align__(16) float aS[4][32];

    const int tid  = threadIdx.x;
    const int lane = tid & 63;
    const int w    = tid >> 6;
    const int quad = lane >> 4;
    const int l16  = lane & 15;

    const int bid = blockIdx.x;
    const int qt  = 7 - (bid >> 7);
    const int bh  = bid & 127;
    const int b   = bh >> 4;
    const int h   = bh & 15;

    u16* qb        = qkv + (size_t)b * 1024 * 3072;
    const u16* vtb = vt + (size_t)bh * 64 * 1024;

    const int qrow0 = qt * 128 + w * 32;

    // async staging geometry: per pass p, lane l -> row w*16 + p*8 + (l>>3),
    // global chunk (l&7) ^ (l>>3)  -> LDS slot (r, c) holds chunk c ^ (r&7)
    const int srow8 = lane >> 3;              // 0..7
    const int scg   = (lane & 7) ^ srow8;     // swizzled global chunk

    short8 qf[2][2];
#pragma unroll
    for (int mj = 0; mj < 2; mj++)
#pragma unroll
        for (int ks = 0; ks < 2; ks++) {
            const u16* src = qb + (size_t)(qrow0 + mj * 16 + l16) * 3072 + 1024 + h * 64 + ks * 32 + quad * 8;
            __align__(16) u16 tmp[8];
            *reinterpret_cast<uint4*>(tmp) = *reinterpret_cast<const uint4*>(src);
#pragma unroll
            for (int e = 0; e < 8; e++) tmp[e] = f2bf(bf2f(tmp[e]) * 0.125f);
            qf[mj][ks] = *reinterpret_cast<short8*>(tmp);
        }

    f32x4 oa[2][4] = {};
    float m_run[2] = {-1e30f, -1e30f};
    float l_run[2] = {0.f, 0.f};

    const int jtmax = 2 * qt + 1;
    for (int jt = 0; jt <= jtmax; jt++) {
        const int j0 = jt * 64;
        __syncthreads();
#pragma unroll
        for (int p = 0; p < 2; p++) {
            const int r = w * 16 + p * 8 + srow8;
            gl16(qb + (size_t)(j0 + r) * 3072 + h * 64 + scg * 8, &Ks[(w * 16 + p * 8) * 64]);
            gl16(vtb + (size_t)r * 1024 + j0 + scg * 8,           &Vs[(w * 16 + p * 8) * 64]);
        }
        __syncthreads();   // vmcnt drain -> tiles ready

        if (j0 > qrow0 + 31) continue;

        // S^T = K . Q^T   (A-frag rows = keys; swizzled chunk reads)
        f32x4 s[4][2] = {};
#pragma unroll
        for (int ks = 0; ks < 2; ks++) {
            short8 kf[4];
#pragma unroll
            for (int ti = 0; ti < 4; ti++)
                kf[ti] = *reinterpret_cast<const short8*>(
                    &Ks[(ti * 16 + l16) * 64 + (((ks * 4 + quad) ^ (l16 & 7)) * 8)]);
#pragma unroll
            for (int ti = 0; ti < 4; ti++)
#pragma unroll
                for (int mj = 0; mj < 2; mj++)
                    s[ti][mj] = __builtin_amdgcn_mfma_f32_16x16x32_bf16(kf[ti], qf[mj][ks], s[ti][mj], 0, 0, 0);
        }

        const bool need_mask = (j0 + 63 > qrow0);
#pragma unroll
        for (int mj = 0; mj < 2; mj++) {
            const int mg = qrow0 + mj * 16 + l16;
            if (need_mask) {
#pragma unroll
                for (int ti = 0; ti < 4; ti++)
#pragma unroll
                    for (int r = 0; r < 4; r++)
                        if (j0 + ti * 16 + quad * 4 + r > mg) s[ti][mj][r] = -1e30f;
            }
            float mt = -1e30f;
#pragma unroll
            for (int ti = 0; ti < 4; ti++)
#pragma unroll
                for (int r = 0; r < 4; r++) mt = fmaxf(mt, s[ti][mj][r]);
            mt = fmaxf(mt, __shfl_xor(mt, 16));
            mt = fmaxf(mt, __shfl_xor(mt, 32));
            const float mn    = fmaxf(m_run[mj], mt);
            const float alpha = __expf(m_run[mj] - mn);
            m_run[mj] = mn;
            float ls = 0.f;
#pragma unroll
            for (int ti = 0; ti < 4; ti++)
#pragma unroll
                for (int r = 0; r < 4; r++) {
                    const float p = __expf(s[ti][mj][r] - mn);
                    s[ti][mj][r] = p;
                    ls += p;
                }
            ls += __shfl_xor(ls, 16);
            ls += __shfl_xor(ls, 32);
            l_run[mj] = l_run[mj] * alpha + ls;
            if (lane < 16) aS[w][mj * 16 + l16] = alpha;
#pragma unroll
            for (int ti = 0; ti < 4; ti++) {
                uint2 pk;
                pk.x = (unsigned)f2bf(s[ti][mj][0]) | ((unsigned)f2bf(s[ti][mj][1]) << 16);
                pk.y = (unsigned)f2bf(s[ti][mj][2]) | ((unsigned)f2bf(s[ti][mj][3]) << 16);
                *reinterpret_cast<uint2*>(&Ps[w][(mj * 16 + l16) * SK + ti * 16 + quad * 4]) = pk;
            }
        }

#pragma unroll
        for (int mi = 0; mi < 2; mi++) {
            const f32x4 av = *reinterpret_cast<const f32x4*>(&aS[w][mi * 16 + quad * 4]);
#pragma unroll
            for (int nd = 0; nd < 4; nd++)
#pragma unroll
                for (int r = 0; r < 4; r++) oa[mi][nd][r] *= av[r];
        }

        // O += P . Vt  (B-frag rows = dh; swizzled chunk reads)
#pragma unroll
        for (int ks = 0; ks < 2; ks++) {
            short8 pf[2], vf[4];
#pragma unroll
            for (int mi = 0; mi < 2; mi++)
                pf[mi] = *reinterpret_cast<const short8*>(&Ps[w][(mi * 16 + l16) * SK + ks * 32 + quad * 8]);
#pragma unroll
            for (int nd = 0; nd < 4; nd++)
                vf[nd] = *reinterpret_cast<const short8*>(
                    &Vs[(nd * 16 + l16) * 64 + (((ks * 4 + quad) ^ (l16 & 7)) * 8)]);
#pragma unroll
            for (int mi = 0; mi < 2; mi++)
#pragma unroll
                for (int nd = 0; nd < 4; nd++)
                    oa[mi][nd] = __builtin_amdgcn_mfma_f32_16x16x32_bf16(pf[mi], vf[nd], oa[mi][nd], 0, 0, 0);
        }
    }

    if (lane < 16) { aS[w][l16] = 1.f / l_run[0]; aS[w][16 + l16] = 1.f / l_run[1]; }
#pragma unroll
    for (int mi = 0; mi < 2; mi++) {
        const f32x4 iv = *reinterpret_cast<const f32x4*>(&aS[w][mi * 16 + quad * 4]);
#pragma unroll
        for (int nd = 0; nd < 4; nd++)
#pragma unroll
            for (int r = 0; r < 4; r++) {
                const int row = qrow0 + mi * 16 + quad * 4 + r;
                qb[(size_t)row * 3072 + 1024 + h * 64 + nd * 16 + l16] = f2bf(oa[mi][nd][r] * iv[r]);
            }
    }
}

// ============================================================
// tier-3 fallback: scalar flash attention (known-good from R1)
// ============================================================
__global__ __launch_bounds__(256) void attn_kernel(u16* __restrict__ qkv) {
    const int g  = blockIdx.x * 256 + threadIdx.x;
    const int q  = g & 1023;
    const int bh = g >> 10;
    const int b  = bh >> 4;
    const int h  = bh & 15;
    const size_t base = (size_t)b * 1024 * 3072 + (size_t)h * 64;
    float qv[64];
    {
        const uint4* q4 = reinterpret_cast<const uint4*>(qkv + base + (size_t)q * 3072 + 1024);
#pragma unroll
        for (int c = 0; c < 8; c++) {
            uint4 t = q4[c];
            qv[c*8+0]=bf_lo(t.x); qv[c*8+1]=bf_hi(t.x); qv[c*8+2]=bf_lo(t.y); qv[c*8+3]=bf_hi(t.y);
            qv[c*8+4]=bf_lo(t.z); qv[c*8+5]=bf_hi(t.z); qv[c*8+6]=bf_lo(t.w); qv[c*8+7]=bf_hi(t.w);
        }
    }
    float o[64];
#pragma unroll
    for (int i = 0; i < 64; i++) o[i] = 0.0f;
    float m = -1e30f, l = 0.0f;
    const int jmax = q | 63;
    for (int j = 0; j <= jmax; j++) {
        const uint4* k4 = reinterpret_cast<const uint4*>(qkv + base + (size_t)j * 3072);
        float s = 0.0f;
#pragma unroll
        for (int c = 0; c < 8; c++) {
            uint4 t = k4[c];
            s += qv[c*8+0]*bf_lo(t.x)+qv[c*8+1]*bf_hi(t.x)+qv[c*8+2]*bf_lo(t.y)+qv[c*8+3]*bf_hi(t.y)
               + qv[c*8+4]*bf_lo(t.z)+qv[c*8+5]*bf_hi(t.z)+qv[c*8+6]*bf_lo(t.w)+qv[c*8+7]*bf_hi(t.w);
        }
        s *= 0.125f;
        const bool act = (j <= q);
        if (!act) s = -1e30f;
        const float mn = fmaxf(m, s);
        const float alpha = __expf(m - mn);
        float p = __expf(s - mn);
        if (!act) p = 0.0f;
        l = l * alpha + p;
        const uint4* v4 = reinterpret_cast<const uint4*>(qkv + base + (size_t)j * 3072 + 2048);
#pragma unroll
        for (int c = 0; c < 8; c++) {
            uint4 t = v4[c];
            o[c*8+0]=o[c*8+0]*alpha+p*bf_lo(t.x); o[c*8+1]=o[c*8+1]*alpha+p*bf_hi(t.x);
            o[c*8+2]=o[c*8+2]*alpha+p*bf_lo(t.y); o[c*8+3]=o[c*8+3]*alpha+p*bf_hi(t.y);
            o[c*8+4]=o[c*8+4]*alpha+p*bf_lo(t.z); o[c*8+5]=o[c*8+5]*alpha+p*bf_hi(t.z);
            o[c*8+6]=o[c*8+6]*alpha+p*bf_lo(t.w); o[c*8+7]=o[c*8+7]*alpha+p*bf_hi(t.w);
        }
        m = mn;
    }
    const float inv = 1.0f / l;
    u16* yrow = qkv + base + (size_t)q * 3072 + 1024;
#pragma unroll
    for (int i = 0; i < 64; i++) yrow[i] = f2bf(o[i] * inv);
}

// ============================================================
extern "C" void kernel_launch(void* const* d_in, const int* in_sizes, int n_in,
                              void* d_out, int out_size, void* d_ws, size_t ws_size,
                              hipStream_t stream) {
    const float* x      = (const float*)d_in[0];   // [8192, 1024]
    const float* w_attn = (const float*)d_in[1];   // [3072, 1024]
    const float* w_proj = (const float*)d_in[2];   // [1024, 1024]
    const float* b_proj = (const float*)d_in[3];   // [1024]
    float* out = (float*)d_out;

    const int M = 8192, K = 1024;
    const size_t QKV = (size_t)8192 * 3072;        // 50.3 MB bf16
    const size_t VT  = (size_t)8 * 16 * 64 * 1024; // 16.8 MB bf16

    u16* qkv = (u16*)d_ws;
    u16* vtb = qkv + QKV;
    u16* xb  = vtb + VT;
    u16* wab = xb + (size_t)8192 * 1024;
    u16* wpb = wab + (size_t)3072 * 1024;

    const size_t need_full = (QKV + VT + (size_t)8192*1024 + (size_t)3072*1024 + (size_t)1024*1024) * 2;
    const size_t need_mid  = (QKV + VT) * 2;

    if (ws_size >= need_full) {
        // one fused convert: dest regions xb|wab|wpb are contiguous
        cvt3_kernel<<<6144, 256, 0, stream>>>(x, 8192 * 1024 / 8,
                                              w_attn, 3072 * 1024 / 8,
                                              w_proj, 1024 * 1024 / 8, xb);
        // qkv-gemm; v-columns written transposed straight into vtb
        gemm_bt_a<false><<<dim3(24, 64), 256, 0, stream>>>(xb, wab, qkv, nullptr, M, 3072, K, K, vtb);
        fattn_kernel<<<1024, 256, 0, stream>>>(qkv, vtb);
        gemm_bt_a<true><<<dim3(8, 64), 256, 0, stream>>>(qkv + 1024, wpb, out, b_proj, M, 1024, K, 3072, nullptr);
    } else if (ws_size >= need_mid) {
        gemm_bt<true, true, false><<<dim3(24, 64), 256, 0, stream>>>(x, w_attn, qkv, nullptr, M, 3072, K, K);
        vtrans_kernel<<<2048, 256, 0, stream>>>(qkv, vtb);
        fattn_kernel<<<1024, 256, 0, stream>>>(qkv, vtb);
        gemm_bt<false, true, true><<<dim3(8, 64), 256, 0, stream>>>(qkv + 1024, w_proj, out, b_proj, M, 1024, K, 3072);
    } else {
        gemm_bt<true, true, false><<<dim3(24, 64), 256, 0, stream>>>(x, w_attn, qkv, nullptr, M, 3072, K, K);
        attn_kernel<<<512, 256, 0, stream>>>(qkv);
        gemm_bt<false, true, true><<<dim3(8, 64), 256, 0, stream>>>(qkv + 1024, w_proj, out, b_proj, M, 1024, K, 3072);
    }
}

// Round 8
// 233.531 us; speedup vs baseline: 1.0288x; 1.0288x over previous
//
#include <hip/hip_runtime.h>
#include <stdint.h>

typedef unsigned short u16;
typedef __attribute__((ext_vector_type(8))) short short8;   // 8 bf16 in 4 VGPRs
typedef __attribute__((ext_vector_type(4))) float f32x4;

// ---------- bf16 helpers ----------
__device__ __forceinline__ float bf2f(u16 u) {
    union { unsigned u; float f; } x; x.u = ((unsigned)u) << 16; return x.f;
}
__device__ __forceinline__ float bf_lo(unsigned w) {
    union { unsigned u; float f; } x; x.u = w << 16; return x.f;
}
__device__ __forceinline__ float bf_hi(unsigned w) {
    union { unsigned u; float f; } x; x.u = w & 0xffff0000u; return x.f;
}
__device__ __forceinline__ u16 f2bf(float f) {   // round-to-nearest-even
    union { float f; unsigned u; } x; x.f = f;
    unsigned r = x.u + 0x7fffu + ((x.u >> 16) & 1u);
    return (u16)(r >> 16);
}
__device__ __forceinline__ uint4 cvt8(const float* p) {
    float4 a = *reinterpret_cast<const float4*>(p);
    float4 b = *reinterpret_cast<const float4*>(p + 4);
    uint4 r;
    r.x = (unsigned)f2bf(a.x) | ((unsigned)f2bf(a.y) << 16);
    r.y = (unsigned)f2bf(a.z) | ((unsigned)f2bf(a.w) << 16);
    r.z = (unsigned)f2bf(b.x) | ((unsigned)f2bf(b.y) << 16);
    r.w = (unsigned)f2bf(b.z) | ((unsigned)f2bf(b.w) << 16);
    return r;
}

// async global -> LDS, 16 bytes per lane (lds dest = wave-uniform base + lane*16)
__device__ __forceinline__ void gl16(const u16* g, u16* l) {
    __builtin_amdgcn_global_load_lds(
        (const __attribute__((address_space(1))) void*)g,
        (__attribute__((address_space(3))) void*)l, 16, 0, 0);
}

// ---------- fp32 -> bf16 bulk converts ----------
__global__ __launch_bounds__(256) void cvt_kernel(const float* __restrict__ in,
                                                  u16* __restrict__ out, int n8) {
    int i = blockIdx.x * 256 + threadIdx.x;
    if (i < n8) *reinterpret_cast<uint4*>(&out[(size_t)i * 8]) = cvt8(&in[(size_t)i * 8]);
}

// fused 3-array convert into one contiguous bf16 region
__global__ __launch_bounds__(256) void cvt3_kernel(const float* __restrict__ a, int na8,
                                                   const float* __restrict__ b, int nb8,
                                                   const float* __restrict__ c, int nc8,
                                                   u16* __restrict__ dst) {
    int i = blockIdx.x * 256 + threadIdx.x;
    const float* src; int off;
    if (i < na8)            { src = a; off = i; }
    else if (i < na8 + nb8) { src = b; off = i - na8; }
    else if (i < na8 + nb8 + nc8) { src = c; off = i - na8 - nb8; }
    else return;
    *reinterpret_cast<uint4*>(&dst[(size_t)i * 8]) = cvt8(&src[(size_t)off * 8]);
}

#define BM 128
#define BN 128
#define BK 32
#define BKA 64

// ============================================================
// m97-class GEMM, BK=64, SINGLE-buffered (best-known: R4/R6 structure).
// global_load_lds width=16 staging; XOR swizzle: LDS slot (row r, chunk c)
// holds global chunk c ^ (r&7); ds_read_b128 is serviced in 8-lane groups
// and 8 consecutive lanes cover all 8 chunks -> 0 bank conflicts (measured).
// If vt != nullptr, blocks with col0 >= 2048 write transposed V:
// vt[(b*1024 + (col-2048))*1024 + t]  (fused vtrans, saves a kernel).
// NOTE (R5 lesson, m99/m132 re-measured): do NOT double-buffer this loop —
// 64KB LDS halves blocks/CU; inter-block overlap beats intra-block prefetch.
// ============================================================
template<bool CF32>
__global__ __launch_bounds__(256) void gemm_bt_a(const u16* __restrict__ A,
                                                 const u16* __restrict__ W,
                                                 void* __restrict__ Cv,
                                                 const float* __restrict__ bias,
                                                 int M, int N, int K, int lda,
                                                 u16* __restrict__ vt) {
    __shared__ __align__(16) u16 As[BM * BKA];   // 16 KB
    __shared__ __align__(16) u16 Ws[BN * BKA];   // 16 KB

    const int tid  = threadIdx.x;
    const int lane = tid & 63;
    const int w    = tid >> 6;
    const int wr   = w >> 1;
    const int wc   = w & 1;
    const int quad = lane >> 4;
    const int l16  = lane & 15;

    const int row0 = blockIdx.y * BM;
    const int col0 = blockIdx.x * BN;

    // staging: pass p covers rows p*32 + w*8 + (l>>3); global chunk (l&7)^(l>>3)
    const int srow = w * 8 + (lane >> 3);
    const int gc   = (lane & 7) ^ (lane >> 3);

    const u16* gA[4]; const u16* gW[4]; u16* lA[4]; u16* lW[4];
#pragma unroll
    for (int p = 0; p < 4; p++) {
        gA[p] = A + (size_t)(row0 + p * 32 + srow) * lda + gc * 8;
        gW[p] = W + (size_t)(col0 + p * 32 + srow) * K  + gc * 8;
        lA[p] = &As[(p * 32 + w * 8) * BKA];
        lW[p] = &Ws[(p * 32 + w * 8) * BKA];
    }

    // swizzled frag-read column: chunk (ks*4+quad) ^ (l16&7)
    const int cr0 = (quad ^ (l16 & 7)) * 8;

    f32x4 acc[4][4] = {};

    for (int k0 = 0; k0 < K; k0 += BKA) {
        __syncthreads();
#pragma unroll
        for (int p = 0; p < 4; p++) {
            gl16(gA[p] + k0, lA[p]);
            gl16(gW[p] + k0, lW[p]);
        }
        __syncthreads();   // vmcnt drain before barrier (m97 structure)

#pragma unroll
        for (int ks = 0; ks < 2; ks++) {
            const int cc = cr0 ^ (ks * 32);
            short8 af[4], bfr[4];
#pragma unroll
            for (int i = 0; i < 4; i++)
                af[i] = *reinterpret_cast<const short8*>(&As[(wr * 64 + i * 16 + l16) * BKA + cc]);
#pragma unroll
            for (int j = 0; j < 4; j++)
                bfr[j] = *reinterpret_cast<const short8*>(&Ws[(wc * 64 + j * 16 + l16) * BKA + cc]);
#pragma unroll
            for (int i = 0; i < 4; i++)
#pragma unroll
                for (int j = 0; j < 4; j++)
                    acc[i][j] = __builtin_amdgcn_mfma_f32_16x16x32_bf16(af[i], bfr[j], acc[i][j], 0, 0, 0);
        }
    }

    // epilogue: C/D layout col=lane&15, row=quad*4+reg  [verified m89/m91]
    if (vt != nullptr && col0 >= 2048) {
        // fused V-transpose: 4 consecutive t per lane -> one 8B store
        const int b = row0 >> 10;
#pragma unroll
        for (int j = 0; j < 4; j++) {
            const int hd = col0 - 2048 + wc * 64 + j * 16 + l16;   // h*64+dh
            u16* dstc = vt + (size_t)(b * 1024 + hd) * 1024 + (row0 & 1023) + wr * 64;
#pragma unroll
            for (int i = 0; i < 4; i++) {
                const int t0 = i * 16 + quad * 4;
                u16 pk[4];
#pragma unroll
                for (int r = 0; r < 4; r++) pk[r] = f2bf(acc[i][j][r]);
                *reinterpret_cast<uint2*>(dstc + t0) = *reinterpret_cast<uint2*>(pk);
            }
        }
    } else {
#pragma unroll
        for (int j = 0; j < 4; j++) {
            const int col = col0 + wc * 64 + j * 16 + l16;
            const float bval = bias ? bias[col] : 0.0f;
#pragma unroll
            for (int i = 0; i < 4; i++) {
#pragma unroll
                for (int r = 0; r < 4; r++) {
                    const int row = row0 + wr * 64 + i * 16 + quad * 4 + r;
                    if (CF32) ((float*)Cv)[(size_t)row * N + col] = acc[i][j][r] + bval;
                    else      ((u16*)Cv)[(size_t)row * N + col]  = f2bf(acc[i][j][r] + bval);
                }
            }
        }
    }
}

// ============================================================
// fallback GEMM (fp32 staging paths, known-good R2)
// ============================================================
template<bool AF32, bool WF32, bool CF32>
__global__ __launch_bounds__(256) void gemm_bt(const void* __restrict__ Av,
                                               const void* __restrict__ Wv,
                                               void* __restrict__ Cv,
                                               const float* __restrict__ bias,
                                               int M, int N, int K, int lda) {
    __shared__ __align__(16) u16 As[BM * BK];
    __shared__ __align__(16) u16 Ws[BN * BK];

    const int tid  = threadIdx.x;
    const int lane = tid & 63;
    const int wave = tid >> 6;
    const int wr   = wave >> 1;
    const int wc   = wave & 1;
    const int quad = lane >> 4;
    const int l16  = lane & 15;

    const int row0 = blockIdx.y * BM;
    const int col0 = blockIdx.x * BN;

    const int sr = tid >> 2;
    const int sc = (tid & 3) * 8;

    f32x4 acc[4][4] = {};

    for (int k0 = 0; k0 < K; k0 += BK) {
        __syncthreads();
        if (AF32) {
            const float* A = (const float*)Av;
            *reinterpret_cast<uint4*>(&As[(sr)      * BK + sc]) = cvt8(&A[(size_t)(row0 + sr)      * lda + k0 + sc]);
            *reinterpret_cast<uint4*>(&As[(sr + 64) * BK + sc]) = cvt8(&A[(size_t)(row0 + sr + 64) * lda + k0 + sc]);
        } else {
            const u16* A = (const u16*)Av;
            *reinterpret_cast<uint4*>(&As[(sr)      * BK + sc]) =
                *reinterpret_cast<const uint4*>(&A[(size_t)(row0 + sr)      * lda + k0 + sc]);
            *reinterpret_cast<uint4*>(&As[(sr + 64) * BK + sc]) =
                *reinterpret_cast<const uint4*>(&A[(size_t)(row0 + sr + 64) * lda + k0 + sc]);
        }
        if (WF32) {
            const float* W = (const float*)Wv;
            *reinterpret_cast<uint4*>(&Ws[(sr)      * BK + sc]) = cvt8(&W[(size_t)(col0 + sr)      * K + k0 + sc]);
            *reinterpret_cast<uint4*>(&Ws[(sr + 64) * BK + sc]) = cvt8(&W[(size_t)(col0 + sr + 64) * K + k0 + sc]);
        } else {
            const u16* W = (const u16*)Wv;
            *reinterpret_cast<uint4*>(&Ws[(sr)      * BK + sc]) =
                *reinterpret_cast<const uint4*>(&W[(size_t)(col0 + sr)      * K + k0 + sc]);
            *reinterpret_cast<uint4*>(&Ws[(sr + 64) * BK + sc]) =
                *reinterpret_cast<const uint4*>(&W[(size_t)(col0 + sr + 64) * K + k0 + sc]);
        }
        __syncthreads();

        short8 af[4], bfr[4];
#pragma unroll
        for (int i = 0; i < 4; i++)
            af[i] = *reinterpret_cast<const short8*>(&As[(wr * 64 + i * 16 + l16) * BK + quad * 8]);
#pragma unroll
        for (int j = 0; j < 4; j++)
            bfr[j] = *reinterpret_cast<const short8*>(&Ws[(wc * 64 + j * 16 + l16) * BK + quad * 8]);

#pragma unroll
        for (int i = 0; i < 4; i++)
#pragma unroll
            for (int j = 0; j < 4; j++)
                acc[i][j] = __builtin_amdgcn_mfma_f32_16x16x32_bf16(af[i], bfr[j], acc[i][j], 0, 0, 0);
    }

#pragma unroll
    for (int j = 0; j < 4; j++) {
        const int col = col0 + wc * 64 + j * 16 + l16;
        const float bval = bias ? bias[col] : 0.0f;
#pragma unroll
        for (int i = 0; i < 4; i++) {
#pragma unroll
            for (int r = 0; r < 4; r++) {
                const int row = row0 + wr * 64 + i * 16 + quad * 4 + r;
                if (CF32) ((float*)Cv)[(size_t)row * N + col] = acc[i][j][r] + bval;
                else      ((u16*)Cv)[(size_t)row * N + col]  = f2bf(acc[i][j][r] + bval);
            }
        }
    }
}

// ============================================================
// V transpose (fallback tiers only): qkv v-section -> Vt[b][h][dh][t]
// ============================================================
__global__ __launch_bounds__(256) void vtrans_kernel(const u16* __restrict__ qkv,
                                                     u16* __restrict__ vt) {
    const int bid = blockIdx.x;
    const int tt = bid & 15, h = (bid >> 4) & 15, b = bid >> 8;
    const int t0 = tt * 64;
    __shared__ __align__(16) u16 tile[64 * 72];
    const int tr = threadIdx.x >> 2, tc = (threadIdx.x & 3) * 16;
    const u16* src = qkv + (size_t)(b * 1024 + t0 + tr) * 3072 + 2048 + h * 64 + tc;
    *reinterpret_cast<uint4*>(&tile[tr * 72 + tc])     = *reinterpret_cast<const uint4*>(src);
    *reinterpret_cast<uint4*>(&tile[tr * 72 + tc + 8]) = *reinterpret_cast<const uint4*>(src + 8);
    __syncthreads();
    const int dh = tr, t1 = tc;
    __align__(16) u16 buf[16];
#pragma unroll
    for (int i = 0; i < 16; i++) buf[i] = tile[(t1 + i) * 72 + dh];
    u16* dst = vt + ((size_t)(b * 16 + h) * 64 + dh) * 1024 + t0 + t1;
    *reinterpret_cast<uint4*>(dst)     = *reinterpret_cast<uint4*>(&buf[0]);
    *reinterpret_cast<uint4*>(dst + 8) = *reinterpret_cast<uint4*>(&buf[8]);
}

// ============================================================
// MFMA flash attention (S^T formulation) — R5 staging restored.
// NOTE (R6 lesson): global_load_lds regressed here (+9 µs) — only 4
// loads/wave/tile can't amortize the DMA issue+drain; vector-load +
// ds_write lets the compiler hoist loads and overlap softmax VALU.
// ============================================================
#define SK 72

__global__ __launch_bounds__(256) void fattn_kernel(u16* __restrict__ qkv,
                                                    const u16* __restrict__ vt) {
    __shared__ __align__(16) u16 Ks[64 * SK];
    __shared__ __align__(16) u16 Vs[64 * SK];
    __shared__ __align__(16) u16 Ps[4][32 * SK];
    __shared__ __align__(16) float aS[4][32];

    const int tid  = threadIdx.x;
    const int lane = tid & 63;
    const int w    = tid >> 6;
    const int quad = lane >> 4;
    const int l16  = lane & 15;

    const int bid = blockIdx.x;
    const int qt  = 7 - (bid >> 7);
    const int bh  = bid & 127;
    const int b   = bh >> 4;
    const int h   = bh & 15;

    u16* qb        = qkv + (size_t)b * 1024 * 3072;
    const u16* vtb = vt + (size_t)bh * 64 * 1024;

    const int qrow0 = qt * 128 + w * 32;

    short8 qf[2][2];
#pragma unroll
    for (int mj = 0; mj < 2; mj++)
#pragma unroll
        for (int ks = 0; ks < 2; ks++) {
            const u16* src = qb + (size_t)(qrow0 + mj * 16 + l16) * 3072 + 1024 + h * 64 + ks * 32 + quad * 8;
            __align__(16) u16 tmp[8];
            *reinterpret_cast<uint4*>(tmp) = *reinterpret_cast<const uint4*>(src);
#pragma unroll
            for (int e = 0; e < 8; e++) tmp[e] = f2bf(bf2f(tmp[e]) * 0.125f);
            qf[mj][ks] = *reinterpret_cast<short8*>(tmp);
        }

    f32x4 oa[2][4] = {};
    float m_run[2] = {-1e30f, -1e30f};
    float l_run[2] = {0.f, 0.f};

    const int jtmax = 2 * qt + 1;
    for (int jt = 0; jt <= jtmax; jt++) {
        const int j0 = jt * 64;
        __syncthreads();
        {
            const int sr = tid >> 2, sc = (tid & 3) * 8;
            const u16* kg = qb + (size_t)(j0 + sr) * 3072 + h * 64;
            *reinterpret_cast<uint4*>(&Ks[sr * SK + sc])      = *reinterpret_cast<const uint4*>(kg + sc);
            *reinterpret_cast<uint4*>(&Ks[sr * SK + sc + 32]) = *reinterpret_cast<const uint4*>(kg + sc + 32);
            const u16* vg = vtb + (size_t)sr * 1024 + j0;
            *reinterpret_cast<uint4*>(&Vs[sr * SK + sc])      = *reinterpret_cast<const uint4*>(vg + sc);
            *reinterpret_cast<uint4*>(&Vs[sr * SK + sc + 32]) = *reinterpret_cast<const uint4*>(vg + sc + 32);
        }
        __syncthreads();

        if (j0 > qrow0 + 31) continue;

        f32x4 s[4][2] = {};
#pragma unroll
        for (int ks = 0; ks < 2; ks++) {
            short8 kf[4];
#pragma unroll
            for (int ti = 0; ti < 4; ti++)
                kf[ti] = *reinterpret_cast<const short8*>(&Ks[(ti * 16 + l16) * SK + ks * 32 + quad * 8]);
#pragma unroll
            for (int ti = 0; ti < 4; ti++)
#pragma unroll
                for (int mj = 0; mj < 2; mj++)
                    s[ti][mj] = __builtin_amdgcn_mfma_f32_16x16x32_bf16(kf[ti], qf[mj][ks], s[ti][mj], 0, 0, 0);
        }

        const bool need_mask = (j0 + 63 > qrow0);
#pragma unroll
        for (int mj = 0; mj < 2; mj++) {
            const int mg = qrow0 + mj * 16 + l16;
            if (need_mask) {
#pragma unroll
                for (int ti = 0; ti < 4; ti++)
#pragma unroll
                    for (int r = 0; r < 4; r++)
                        if (j0 + ti * 16 + quad * 4 + r > mg) s[ti][mj][r] = -1e30f;
            }
            float mt = -1e30f;
#pragma unroll
            for (int ti = 0; ti < 4; ti++)
#pragma unroll
                for (int r = 0; r < 4; r++) mt = fmaxf(mt, s[ti][mj][r]);
            mt = fmaxf(mt, __shfl_xor(mt, 16));
            mt = fmaxf(mt, __shfl_xor(mt, 32));
            const float mn    = fmaxf(m_run[mj], mt);
            const float alpha = __expf(m_run[mj] - mn);
            m_run[mj] = mn;
            float ls = 0.f;
#pragma unroll
            for (int ti = 0; ti < 4; ti++)
#pragma unroll
                for (int r = 0; r < 4; r++) {
                    const float p = __expf(s[ti][mj][r] - mn);
                    s[ti][mj][r] = p;
                    ls += p;
                }
            ls += __shfl_xor(ls, 16);
            ls += __shfl_xor(ls, 32);
            l_run[mj] = l_run[mj] * alpha + ls;
            if (lane < 16) aS[w][mj * 16 + l16] = alpha;
#pragma unroll
            for (int ti = 0; ti < 4; ti++) {
                uint2 pk;
                pk.x = (unsigned)f2bf(s[ti][mj][0]) | ((unsigned)f2bf(s[ti][mj][1]) << 16);
                pk.y = (unsigned)f2bf(s[ti][mj][2]) | ((unsigned)f2bf(s[ti][mj][3]) << 16);
                *reinterpret_cast<uint2*>(&Ps[w][(mj * 16 + l16) * SK + ti * 16 + quad * 4]) = pk;
            }
        }

#pragma unroll
        for (int mi = 0; mi < 2; mi++) {
            const f32x4 av = *reinterpret_cast<const f32x4*>(&aS[w][mi * 16 + quad * 4]);
#pragma unroll
            for (int nd = 0; nd < 4; nd++)
#pragma unroll
                for (int r = 0; r < 4; r++) oa[mi][nd][r] *= av[r];
        }

#pragma unroll
        for (int ks = 0; ks < 2; ks++) {
            short8 pf[2], vf[4];
#pragma unroll
            for (int mi = 0; mi < 2; mi++)
                pf[mi] = *reinterpret_cast<const short8*>(&Ps[w][(mi * 16 + l16) * SK + ks * 32 + quad * 8]);
#pragma unroll
            for (int nd = 0; nd < 4; nd++)
                vf[nd] = *reinterpret_cast<const short8*>(&Vs[(nd * 16 + l16) * SK + ks * 32 + quad * 8]);
#pragma unroll
            for (int mi = 0; mi < 2; mi++)
#pragma unroll
                for (int nd = 0; nd < 4; nd++)
                    oa[mi][nd] = __builtin_amdgcn_mfma_f32_16x16x32_bf16(pf[mi], vf[nd], oa[mi][nd], 0, 0, 0);
        }
    }

    if (lane < 16) { aS[w][l16] = 1.f / l_run[0]; aS[w][16 + l16] = 1.f / l_run[1]; }
#pragma unroll
    for (int mi = 0; mi < 2; mi++) {
        const f32x4 iv = *reinterpret_cast<const f32x4*>(&aS[w][mi * 16 + quad * 4]);
#pragma unroll
        for (int nd = 0; nd < 4; nd++)
#pragma unroll
            for (int r = 0; r < 4; r++) {
                const int row = qrow0 + mi * 16 + quad * 4 + r;
                qb[(size_t)row * 3072 + 1024 + h * 64 + nd * 16 + l16] = f2bf(oa[mi][nd][r] * iv[r]);
            }
    }
}

// ============================================================
// tier-3 fallback: scalar flash attention (known-good from R1)
// ============================================================
__global__ __launch_bounds__(256) void attn_kernel(u16* __restrict__ qkv) {
    const int g  = blockIdx.x * 256 + threadIdx.x;
    const int q  = g & 1023;
    const int bh = g >> 10;
    const int b  = bh >> 4;
    const int h  = bh & 15;
    const size_t base = (size_t)b * 1024 * 3072 + (size_t)h * 64;
    float qv[64];
    {
        const uint4* q4 = reinterpret_cast<const uint4*>(qkv + base + (size_t)q * 3072 + 1024);
#pragma unroll
        for (int c = 0; c < 8; c++) {
            uint4 t = q4[c];
            qv[c*8+0]=bf_lo(t.x); qv[c*8+1]=bf_hi(t.x); qv[c*8+2]=bf_lo(t.y); qv[c*8+3]=bf_hi(t.y);
            qv[c*8+4]=bf_lo(t.z); qv[c*8+5]=bf_hi(t.z); qv[c*8+6]=bf_lo(t.w); qv[c*8+7]=bf_hi(t.w);
        }
    }
    float o[64];
#pragma unroll
    for (int i = 0; i < 64; i++) o[i] = 0.0f;
    float m = -1e30f, l = 0.0f;
    const int jmax = q | 63;
    for (int j = 0; j <= jmax; j++) {
        const uint4* k4 = reinterpret_cast<const uint4*>(qkv + base + (size_t)j * 3072);
        float s = 0.0f;
#pragma unroll
        for (int c = 0; c < 8; c++) {
            uint4 t = k4[c];
            s += qv[c*8+0]*bf_lo(t.x)+qv[c*8+1]*bf_hi(t.x)+qv[c*8+2]*bf_lo(t.y)+qv[c*8+3]*bf_hi(t.y)
               + qv[c*8+4]*bf_lo(t.z)+qv[c*8+5]*bf_hi(t.z)+qv[c*8+6]*bf_lo(t.w)+qv[c*8+7]*bf_hi(t.w);
        }
        s *= 0.125f;
        const bool act = (j <= q);
        if (!act) s = -1e30f;
        const float mn = fmaxf(m, s);
        const float alpha = __expf(m - mn);
        float p = __expf(s - mn);
        if (!act) p = 0.0f;
        l = l * alpha + p;
        const uint4* v4 = reinterpret_cast<const uint4*>(qkv + base + (size_t)j * 3072 + 2048);
#pragma unroll
        for (int c = 0; c < 8; c++) {
            uint4 t = v4[c];
            o[c*8+0]=o[c*8+0]*alpha+p*bf_lo(t.x); o[c*8+1]=o[c*8+1]*alpha+p*bf_hi(t.x);
            o[c*8+2]=o[c*8+2]*alpha+p*bf_lo(t.y); o[c*8+3]=o[c*8+3]*alpha+p*bf_hi(t.y);
            o[c*8+4]=o[c*8+4]*alpha+p*bf_lo(t.z); o[c*8+5]=o[c*8+5]*alpha+p*bf_hi(t.z);
            o[c*8+6]=o[c*8+6]*alpha+p*bf_lo(t.w); o[c*8+7]=o[c*8+7]*alpha+p*bf_hi(t.w);
        }
        m = mn;
    }
    const float inv = 1.0f / l;
    u16* yrow = qkv + base + (size_t)q * 3072 + 1024;
#pragma unroll
    for (int i = 0; i < 64; i++) yrow[i] = f2bf(o[i] * inv);
}

// ============================================================
extern "C" void kernel_launch(void* const* d_in, const int* in_sizes, int n_in,
                              void* d_out, int out_size, void* d_ws, size_t ws_size,
                              hipStream_t stream) {
    const float* x      = (const float*)d_in[0];   // [8192, 1024]
    const float* w_attn = (const float*)d_in[1];   // [3072, 1024]
    const float* w_proj = (const float*)d_in[2];   // [1024, 1024]
    const float* b_proj = (const float*)d_in[3];   // [1024]
    float* out = (float*)d_out;

    const int M = 8192, K = 1024;
    const size_t QKV = (size_t)8192 * 3072;        // 50.3 MB bf16
    const size_t VT  = (size_t)8 * 16 * 64 * 1024; // 16.8 MB bf16

    u16* qkv = (u16*)d_ws;
    u16* vtb = qkv + QKV;
    u16* xb  = vtb + VT;
    u16* wab = xb + (size_t)8192 * 1024;
    u16* wpb = wab + (size_t)3072 * 1024;

    const size_t need_full = (QKV + VT + (size_t)8192*1024 + (size_t)3072*1024 + (size_t)1024*1024) * 2;
    const size_t need_mid  = (QKV + VT) * 2;

    if (ws_size >= need_full) {
        // one fused convert: dest regions xb|wab|wpb are contiguous
        cvt3_kernel<<<6144, 256, 0, stream>>>(x, 8192 * 1024 / 8,
                                              w_attn, 3072 * 1024 / 8,
                                              w_proj, 1024 * 1024 / 8, xb);
        // qkv-gemm; v-columns written transposed straight into vtb
        gemm_bt_a<false><<<dim3(24, 64), 256, 0, stream>>>(xb, wab, qkv, nullptr, M, 3072, K, K, vtb);
        fattn_kernel<<<1024, 256, 0, stream>>>(qkv, vtb);
        gemm_bt_a<true><<<dim3(8, 64), 256, 0, stream>>>(qkv + 1024, wpb, out, b_proj, M, 1024, K, 3072, nullptr);
    } else if (ws_size >= need_mid) {
        gemm_bt<true, true, false><<<dim3(24, 64), 256, 0, stream>>>(x, w_attn, qkv, nullptr, M, 3072, K, K);
        vtrans_kernel<<<2048, 256, 0, stream>>>(qkv, vtb);
        fattn_kernel<<<1024, 256, 0, stream>>>(qkv, vtb);
        gemm_bt<false, true, true><<<dim3(8, 64), 256, 0, stream>>>(qkv + 1024, w_proj, out, b_proj, M, 1024, K, 3072);
    } else {
        gemm_bt<true, true, false><<<dim3(24, 64), 256, 0, stream>>>(x, w_attn, qkv, nullptr, M, 3072, K, K);
        attn_kernel<<<512, 256, 0, stream>>>(qkv);
        gemm_bt<false, true, true><<<dim3(8, 64), 256, 0, stream>>>(qkv + 1024, w_proj, out, b_proj, M, 1024, K, 3072);
    }
}